// Round 22
// baseline (157.965 us; speedup 1.0000x reference)
//
#include <hip/hip_runtime.h>
#include <hip/hip_fp16.h>

static constexpr float SLOPE = 0.2f;

#define NPB 256          // nodes per bucket
#define NBMAX 512        // max buckets
#define CAP 10240        // packed-edge capacity per bucket (= 1024 threads x 10)
#define EPB 4096         // edges per bin block (grid 782, 4 blocks/CU)

// ---------------------------------------------------------------------------
// Monotone float<->uint key for exact atomicMax on floats of either sign.
__device__ __forceinline__ unsigned fkey(float f) {
    unsigned u = __float_as_uint(f);
    return (u & 0x80000000u) ? ~u : (u | 0x80000000u);
}
__device__ __forceinline__ float fdekey(unsigned k) {
    unsigned u = (k & 0x80000000u) ? (k & 0x7FFFFFFFu) : ~k;
    return __uint_as_float(u);
}

__device__ __forceinline__ int load_idx(const void* ei, int is64, long long pos) {
    return is64 ? (int)((const long long*)ei)[pos] : ((const int*)ei)[pos];
}

// ---------------------------------------------------------------------------
// Zero the gkeys + bfill workspace.
__global__ void zero_kernel(unsigned* __restrict__ gkeys, int* __restrict__ bfill) {
    int t = threadIdx.x;
    if (t < 2) gkeys[t] = 0u;
    for (int i = t; i < NBMAX; i += 256) bfill[i] = 0;
}

// ---------------------------------------------------------------------------
// Pass 1: bin edges by dst bucket. LDS-staged sort-by-bucket write-out
// (histogram -> scan -> LDS place -> bulk reserve -> linear write-out).
// 512-thread blocks, EPB=4096 -> 30KB LDS -> 4 blocks/CU, grid 782.
__global__ void __launch_bounds__(512) bin_kernel(
        const void* __restrict__ ei, int* __restrict__ bfill,
        unsigned int* __restrict__ packed, int e, int nb) {
    __shared__ int hist[NBMAX];            // counts, then gbase after reserve
    __shared__ int lbase[NBMAX];           // local exclusive scan
    __shared__ int cur[NBMAX];             // placement cursor
    __shared__ unsigned staged[EPB];       // 16KB bucket-sorted packed words
    __shared__ unsigned short sbkt[EPB];   // 8KB bucket id per slot
    __shared__ int sflag;
    int t = threadIdx.x;
    if (t < 64) {
        unsigned hi = ((const unsigned*)ei)[2 * t + 1];
        unsigned long long b = __ballot(hi != 0u);
        if (t == 0) sflag = (b == 0ull) ? 1 : 0;
    }
    if (t < NBMAX) hist[t] = 0;
    __syncthreads();
    int is64 = sflag;
    long long e0 = (long long)blockIdx.x * EPB;
    int cnt = (int)min((long long)EPB, (long long)e - e0);
    // phase A: load 8 contiguous edges/thread into registers + histogram
    int sr[8], dr[8];
    if (!is64 && t * 8 + 7 < cnt) {
        const uint4* ps = (const uint4*)((const int*)ei + e0) + t * 2;
        const uint4* pd = (const uint4*)((const int*)ei + e + e0) + t * 2;
        uint4 s0 = ps[0], s1 = ps[1], d0 = pd[0], d1 = pd[1];
        sr[0] = s0.x; sr[1] = s0.y; sr[2] = s0.z; sr[3] = s0.w;
        sr[4] = s1.x; sr[5] = s1.y; sr[6] = s1.z; sr[7] = s1.w;
        dr[0] = d0.x; dr[1] = d0.y; dr[2] = d0.z; dr[3] = d0.w;
        dr[4] = d1.x; dr[5] = d1.y; dr[6] = d1.z; dr[7] = d1.w;
    } else {
#pragma unroll
        for (int r = 0; r < 8; ++r) {
            int i = t * 8 + r;
            dr[r] = -1;
            if (i < cnt) {
                sr[r] = load_idx(ei, is64, e0 + i);
                dr[r] = load_idx(ei, is64, (long long)e + e0 + i);
            }
        }
    }
#pragma unroll
    for (int r = 0; r < 8; ++r)
        if (dr[r] >= 0) atomicAdd(&hist[dr[r] >> 8], 1);
    __syncthreads();
    // block-local exclusive scan over NBMAX buckets (thread t owns bucket t)
    int v = (t < NBMAX) ? hist[t] : 0;
    if (t < NBMAX) lbase[t] = v;
    __syncthreads();
    for (int off = 1; off < NBMAX; off <<= 1) {
        int y = (t < NBMAX && t >= off) ? lbase[t - off] : 0;
        __syncthreads();
        if (t < NBMAX) lbase[t] += y;
        __syncthreads();
    }
    if (t < NBMAX) {
        lbase[t] -= v;          // exclusive
        cur[t] = lbase[t];
        hist[t] = (v > 0) ? atomicAdd(&bfill[t], v) : 0;  // hist becomes gbase
    }
    __syncthreads();
    // phase B: place into LDS staged, sorted by bucket
#pragma unroll
    for (int r = 0; r < 8; ++r) {
        if (dr[r] >= 0) {
            int bk = dr[r] >> 8;
            int lp = atomicAdd(&cur[bk], 1);
            staged[lp] = ((unsigned)(dr[r] & 255) << 17) | (unsigned)sr[r];
            sbkt[lp] = (unsigned short)bk;
        }
    }
    __syncthreads();
    // phase C: coalesced linear write-out
    for (int i = t; i < cnt; i += 512) {
        int bk = sbkt[i];
        int within = hist[bk] + (i - lbase[bk]);
        if (within < CAP)
            packed[(long long)bk * CAP + within] = staged[i];
    }
}

// ---------------------------------------------------------------------------
// Per-node feature transform: h = x @ W; alpha_src/alpha_dst dot products.
// Writes h in fp32 (self-term, next layer input) AND fp16 (h16, 3.2MB
// gather table).
template <int NF>
__global__ void feat_kernel(const float* __restrict__ x, const float* __restrict__ W,
                            const float* __restrict__ avs, const float* __restrict__ avd,
                            float* __restrict__ h, __half* __restrict__ h16,
                            float* __restrict__ as, float* __restrict__ ad, int n) {
    __shared__ float sW[NF * 16];
    __shared__ float sa[32];
    int t = threadIdx.x;
    if (t < NF * 16) sW[t] = W[t];
    if (t < 16) sa[t] = avs[t];
    else if (t < 32) sa[t] = avd[t - 16];
    __syncthreads();
    int nid = blockIdx.x * blockDim.x + t;
    if (nid >= n) return;
    float xi[NF];
#pragma unroll
    for (int f = 0; f < NF; ++f) xi[f] = x[(long long)nid * NF + f];
    float hv[16];
    float s1 = 0.f, s2 = 0.f;
#pragma unroll
    for (int k = 0; k < 16; ++k) {
        float acc = 0.f;
#pragma unroll
        for (int f = 0; f < NF; ++f) acc = fmaf(xi[f], sW[f * 16 + k], acc);
        hv[k] = acc;
        s1 = fmaf(acc, sa[k], s1);
        s2 = fmaf(acc, sa[16 + k], s2);
    }
    float4* hp = (float4*)(h + (long long)nid * 16);
    hp[0] = make_float4(hv[0], hv[1], hv[2], hv[3]);
    hp[1] = make_float4(hv[4], hv[5], hv[6], hv[7]);
    hp[2] = make_float4(hv[8], hv[9], hv[10], hv[11]);
    hp[3] = make_float4(hv[12], hv[13], hv[14], hv[15]);
    unsigned u[8];
#pragma unroll
    for (int q = 0; q < 8; ++q) {
        __half2 p2 = __halves2half2(__float2half(hv[2 * q]), __float2half(hv[2 * q + 1]));
        u[q] = *(unsigned*)&p2;
    }
    uint4* hp16 = (uint4*)(h16 + (long long)nid * 16);
    hp16[0] = make_uint4(u[0], u[1], u[2], u[3]);
    hp16[1] = make_uint4(u[4], u[5], u[6], u[7]);
    as[nid] = s1;
    ad[nid] = s2;
}

// ---------------------------------------------------------------------------
// EDGE-PARALLEL two-pass softmax aggregation, one 1024-thread block per
// bucket. SORT + REGISTER-FLUSH: pass 1 loads edges into regs, computes the
// per-node TRUE max (one u32 atomicMax) and a per-node histogram; after a
// block scan, edges are scattered into an LDS array SORTED BY NODE in an
// interleaved layout phys = q + i*1026 (thread q's 10 consecutive logical
// edges are conflict-free across the wave). Pass 2: each thread walks its 10
// consecutive (node-sorted) edges, accumulating the packed channel-pair
// encodings in REGISTERS, and flushes 9 u64 atomics only at node boundaries
// (~1.3 runs per thread) — vs 9 u64 per edge before. Sum-of-encodings is
// bitwise identical to per-edge atomics (integer addition is exactly
// associative/commutative) => BITWISE ORDER-INDEPENDENT for any schedule.
// Weights w = exp(e - m_node + 21 ln2) <= 2^21 => pair sums < 2^30; count
// (den high word) recovers exact carries at output. den >= 2^21 => error
// ~1.5e-5.
__global__ void __launch_bounds__(1024) aggr_kernel(
        const float* __restrict__ h, const __half* __restrict__ h16,
        const float* __restrict__ as, const float* __restrict__ ad,
        const unsigned* __restrict__ packed, const int* __restrict__ bfill,
        const float* __restrict__ bias,
        float* __restrict__ out, int n, int do_relu) {
    __shared__ unsigned long long accS[NPB * 9];  // 18KB: +0..7 ch-pairs, +8 cnt|den
    __shared__ unsigned maxS[NPB];                // fkey(per-node max e)
    __shared__ float ccS[NPB];
    __shared__ float adnS[NPB];
    __shared__ int histN[NPB];
    __shared__ int curN[NPB];
    __shared__ unsigned sorted[10 * 1026];        // 41KB interleaved node-sorted
    int b = blockIdx.x, t = threadIdx.x;
    int cnt = min(bfill[b], CAP);
    long long pb = (long long)b * CAP;
    // (a) init per-node state
    if (t < NPB) {
        int node = b * NPB + t;
        float adn = (node < n) ? ad[node] : 0.f;
        adnS[t] = adn;
        float es = (node < n) ? (as[node] + adn) : 0.f;
        es = fmaxf(es, SLOPE * es);
        maxS[t] = fkey(es);
        histN[t] = 0;
    }
    __syncthreads();
    // (b) pass 1: strided load into regs; per-node max + histogram
    unsigned pk[10];
#pragma unroll
    for (int r = 0; r < 10; ++r) {
        int j = t + (r << 10);
        pk[r] = 0xFFFFFFFFu;
        if (j < cnt) {
            unsigned p = packed[pb + j];
            int dl = p >> 17;
            int s = (int)(p & 0x1FFFF);
            float e2 = as[s] + adnS[dl];
            e2 = fmaxf(e2, SLOPE * e2);
            pk[r] = p;
            atomicMax(&maxS[dl], fkey(e2));
            atomicAdd(&histN[dl], 1);
        }
    }
    __syncthreads();
    // (c) scan histN -> exclusive cursor; cc + self-term init
    int v = (t < NPB) ? histN[t] : 0;
    if (t < NPB) curN[t] = v;
    __syncthreads();
    for (int off = 1; off < NPB; off <<= 1) {
        int y = (t < NPB && t >= off) ? curN[t - off] : 0;
        __syncthreads();
        if (t < NPB) curN[t] += y;
        __syncthreads();
    }
    if (t < NPB) {
        curN[t] -= v;                         // exclusive (cursor start)
        int node = b * NPB + t;
        if (node < n) {
            float m = fdekey(maxS[t]);
            float cc = 21.f * 0.69314718f - m;  // w = exp(e+cc) <= 2^21
            ccS[t] = cc;
            float es = as[node] + adnS[t];
            es = fmaxf(es, SLOPE * es);
            float ws = __expf(es + cc);
            unsigned wsi = (unsigned)(int)ws;
            int base = t * 9;
            const float4* hp = (const float4*)(h + (long long)node * 16);
            float4 h0 = hp[0], h1v = hp[1], h2v = hp[2], h3v = hp[3];
            float hv[16] = {h0.x, h0.y, h0.z, h0.w, h1v.x, h1v.y, h1v.z, h1v.w,
                            h2v.x, h2v.y, h2v.z, h2v.w, h3v.x, h3v.y, h3v.z, h3v.w};
#pragma unroll
            for (int q = 0; q < 8; ++q) {
                int t0 = (int)(ws * hv[2 * q]);
                int t1 = (int)(ws * hv[2 * q + 1]);
                accS[base + q] = ((unsigned long long)(unsigned)t1 << 32) +
                                 (unsigned long long)((unsigned)t0 + 0x80000000u);
            }
            accS[base + 8] = (1ull << 32) | wsi;  // count=1, den=ws
        }
    }
    __syncthreads();
    // (d) scatter regs into node-sorted interleaved LDS
#pragma unroll
    for (int r = 0; r < 10; ++r) {
        if (pk[r] != 0xFFFFFFFFu) {
            unsigned p = pk[r];
            int pos = atomicAdd(&curN[p >> 17], 1);
            int q = pos / 10;                 // const divisor -> magic mul
            int i = pos - q * 10;
            sorted[q + i * 1026] = p;
        }
    }
    __syncthreads();
    // (e) pass 2: thread t walks logical [10t, 10t+10) (node-consecutive),
    // register-accumulates, flushes at node boundaries only
    unsigned long long racc[8] = {0, 0, 0, 0, 0, 0, 0, 0};
    unsigned long long rden = 0;
    int curdl = -1;
    int lim = min(10, cnt - t * 10);
    for (int i = 0; i < lim; ++i) {
        unsigned p = sorted[t + i * 1026];
        int dl = p >> 17;
        int s = (int)(p & 0x1FFFF);
        if (dl != curdl) {
            if (curdl >= 0) {
                int base = curdl * 9;
                atomicAdd(&accS[base + 8], rden);
#pragma unroll
                for (int q = 0; q < 8; ++q) atomicAdd(&accS[base + q], racc[q]);
            }
            curdl = dl;
            rden = 0;
#pragma unroll
            for (int q = 0; q < 8; ++q) racc[q] = 0;
        }
        float e2 = as[s] + adnS[dl];
        e2 = fmaxf(e2, SLOPE * e2);
        float w = __expf(e2 + ccS[dl]);
        rden += (1ull << 32) | (unsigned)(int)w;
        const uint4* hr = (const uint4*)(h16 + (long long)s * 16);
        uint4 r0 = hr[0], r1 = hr[1];
        unsigned rr[8] = {r0.x, r0.y, r0.z, r0.w, r1.x, r1.y, r1.z, r1.w};
#pragma unroll
        for (int q = 0; q < 8; ++q) {
            float2 f = __half22float2(*(__half2*)&rr[q]);
            int t0 = (int)(w * f.x);
            int t1 = (int)(w * f.y);
            racc[q] += ((unsigned long long)(unsigned)t1 << 32) +
                       (unsigned long long)((unsigned)t0 + 0x80000000u);
        }
    }
    if (curdl >= 0) {
        int base = curdl * 9;
        atomicAdd(&accS[base + 8], rden);
#pragma unroll
        for (int q = 0; q < 8; ++q) atomicAdd(&accS[base + q], racc[q]);
    }
    __syncthreads();
    // (f) output: unpack pairs with exact carry recovery, divide, bias, relu
    for (int idx = t; idx < NPB * 16; idx += 1024) {
        int i = idx >> 4, k = idx & 15;
        int node = b * NPB + i;
        if (node < n) {
            unsigned long long dpack = accS[i * 9 + 8];
            unsigned kcnt = (unsigned)(dpack >> 32);
            float den = (float)(unsigned)dpack;
            unsigned long long a = accS[i * 9 + (k >> 1)];
            unsigned lo = (unsigned)a, hi = (unsigned)(a >> 32);
            int s0 = (int)(lo - (kcnt << 31));
            float val;
            if ((k & 1) == 0) {
                val = (float)s0;
            } else {
                long long carries =
                    ((((long long)kcnt) << 31) + (long long)s0) >> 32;
                int s1 = (int)(hi - (unsigned)carries);
                val = (float)s1;
            }
            float o = val / den + bias[k];
            if (do_relu) o = fmaxf(o, 0.f);
            out[(long long)node * 16 + k] = o;
        }
    }
}

// ---------------------------------------------------------------------------
extern "C" void kernel_launch(void* const* d_in, const int* in_sizes, int n_in,
                              void* d_out, int out_size, void* d_ws, size_t ws_size,
                              hipStream_t stream) {
    const float* x  = (const float*)d_in[0];
    const void*  ei = d_in[1];
    const float* W1  = (const float*)d_in[2];
    const float* as1 = (const float*)d_in[3];
    const float* ad1 = (const float*)d_in[4];
    const float* b1  = (const float*)d_in[5];
    const float* W2  = (const float*)d_in[6];
    const float* as2 = (const float*)d_in[7];
    const float* ad2 = (const float*)d_in[8];
    const float* b2  = (const float*)d_in[9];
    float* out = (float*)d_out;

    const int n = in_sizes[0] / 14;      // 100000
    const int e = in_sizes[1] / 2;       // 3200000
    const int nb = (n + NPB - 1) / NPB;  // 391 buckets

    char* p = (char*)d_ws;
    auto alloc = [&](size_t bytes) {
        char* r = p;
        p += (bytes + 255) & ~(size_t)255;
        return r;
    };
    unsigned* gkeys  = (unsigned*)alloc(256);
    int*      bfill  = (int*)alloc(NBMAX * 4);
    unsigned* packed = (unsigned*)alloc((size_t)nb * CAP * 4);
    float*    h      = (float*)alloc((size_t)n * 16 * 4);
    __half*   h16    = (__half*)alloc((size_t)n * 16 * 2);
    float*    h1     = (float*)alloc((size_t)n * 16 * 4);
    float*    asb    = (float*)alloc((size_t)n * 4);
    float*    adb    = (float*)alloc((size_t)n * 4);

    zero_kernel<<<1, 256, 0, stream>>>(gkeys, bfill);
    bin_kernel<<<(e + EPB - 1) / EPB, 512, 0, stream>>>(ei, bfill, packed, e, nb);

    // Layer 1
    feat_kernel<14><<<(n + 255) / 256, 256, 0, stream>>>(x, W1, as1, ad1, h, h16, asb, adb, n);
    aggr_kernel<<<nb, 1024, 0, stream>>>(h, h16, asb, adb, packed, bfill, b1, h1, n, 1);
    // Layer 2
    feat_kernel<16><<<(n + 255) / 256, 256, 0, stream>>>(h1, W2, as2, ad2, h, h16, asb, adb, n);
    aggr_kernel<<<nb, 1024, 0, stream>>>(h, h16, asb, adb, packed, bfill, b2, out, n, 0);
}

// Round 23
// 118.518 us; speedup vs baseline: 1.3328x; 1.3328x over previous
//
#include <hip/hip_runtime.h>
#include <hip/hip_fp16.h>

static constexpr float SLOPE = 0.2f;

#define NPB 256          // nodes per bucket
#define NBMAX 512        // max buckets
#define CAP 10240        // packed-edge capacity per bucket (avg ~8184, >20 sigma margin)
#define EPB 8192         // edges per bin block (~21 words/bucket region, line-coalesced)

// ---------------------------------------------------------------------------
// Monotone float<->uint key for exact atomicMax on floats of either sign.
__device__ __forceinline__ unsigned fkey(float f) {
    unsigned u = __float_as_uint(f);
    return (u & 0x80000000u) ? ~u : (u | 0x80000000u);
}
__device__ __forceinline__ float fdekey(unsigned k) {
    unsigned u = (k & 0x80000000u) ? (k & 0x7FFFFFFFu) : ~k;
    return __uint_as_float(u);
}

__device__ __forceinline__ int load_idx(const void* ei, int is64, long long pos) {
    return is64 ? (int)((const long long*)ei)[pos] : ((const int*)ei)[pos];
}

// ---------------------------------------------------------------------------
// Zero the bfill workspace (ws is not re-poisoned between replays).
__global__ void zero_kernel(int* __restrict__ bfill) {
    int t = threadIdx.x;
    for (int i = t; i < NBMAX; i += 256) bfill[i] = 0;
}

// ---------------------------------------------------------------------------
// Pass 1: bin edges by dst bucket. LDS-staged sort-by-bucket write-out
// (histogram -> scan -> LDS place -> bulk reserve -> linear write-out).
// 1024-thread blocks, EPB=8192 (validated R21 config, ~21 words/bucket
// region stays line-coalesced).
__global__ void __launch_bounds__(1024) bin_kernel(
        const void* __restrict__ ei, int* __restrict__ bfill,
        unsigned int* __restrict__ packed, int e, int nb) {
    __shared__ int hist[NBMAX];            // counts, then gbase after reserve
    __shared__ int lbase[NBMAX];           // local exclusive scan
    __shared__ int cur[NBMAX];             // placement cursor
    __shared__ unsigned staged[EPB];       // 32KB bucket-sorted packed words
    __shared__ unsigned short sbkt[EPB];   // 16KB bucket id per slot
    __shared__ int sflag;
    int t = threadIdx.x;
    if (t < 64) {
        unsigned hi = ((const unsigned*)ei)[2 * t + 1];
        unsigned long long b = __ballot(hi != 0u);
        if (t == 0) sflag = (b == 0ull) ? 1 : 0;
    }
    if (t < NBMAX) hist[t] = 0;
    __syncthreads();
    int is64 = sflag;
    long long e0 = (long long)blockIdx.x * EPB;
    int cnt = (int)min((long long)EPB, (long long)e - e0);
    // phase A: load 8 contiguous edges/thread into registers + histogram
    int sr[8], dr[8];
    if (!is64 && t * 8 + 7 < cnt) {
        const uint4* ps = (const uint4*)((const int*)ei + e0) + t * 2;
        const uint4* pd = (const uint4*)((const int*)ei + e + e0) + t * 2;
        uint4 s0 = ps[0], s1 = ps[1], d0 = pd[0], d1 = pd[1];
        sr[0] = s0.x; sr[1] = s0.y; sr[2] = s0.z; sr[3] = s0.w;
        sr[4] = s1.x; sr[5] = s1.y; sr[6] = s1.z; sr[7] = s1.w;
        dr[0] = d0.x; dr[1] = d0.y; dr[2] = d0.z; dr[3] = d0.w;
        dr[4] = d1.x; dr[5] = d1.y; dr[6] = d1.z; dr[7] = d1.w;
    } else {
#pragma unroll
        for (int r = 0; r < 8; ++r) {
            int i = t * 8 + r;
            dr[r] = -1;
            if (i < cnt) {
                sr[r] = load_idx(ei, is64, e0 + i);
                dr[r] = load_idx(ei, is64, (long long)e + e0 + i);
            }
        }
    }
#pragma unroll
    for (int r = 0; r < 8; ++r)
        if (dr[r] >= 0) atomicAdd(&hist[dr[r] >> 8], 1);
    __syncthreads();
    // block-local exclusive scan over NBMAX buckets (thread t owns bucket t)
    int v = (t < NBMAX) ? hist[t] : 0;
    if (t < NBMAX) lbase[t] = v;
    __syncthreads();
    for (int off = 1; off < NBMAX; off <<= 1) {
        int y = (t < NBMAX && t >= off) ? lbase[t - off] : 0;
        __syncthreads();
        if (t < NBMAX) lbase[t] += y;
        __syncthreads();
    }
    if (t < NBMAX) {
        lbase[t] -= v;          // exclusive
        cur[t] = lbase[t];
        hist[t] = (v > 0) ? atomicAdd(&bfill[t], v) : 0;  // hist becomes gbase
    }
    __syncthreads();
    // phase B: place into LDS staged, sorted by bucket
#pragma unroll
    for (int r = 0; r < 8; ++r) {
        if (dr[r] >= 0) {
            int bk = dr[r] >> 8;
            int lp = atomicAdd(&cur[bk], 1);
            staged[lp] = ((unsigned)(dr[r] & 255) << 17) | (unsigned)sr[r];
            sbkt[lp] = (unsigned short)bk;
        }
    }
    __syncthreads();
    // phase C: coalesced linear write-out
    for (int i = t; i < cnt; i += 1024) {
        int bk = sbkt[i];
        int within = hist[bk] + (i - lbase[bk]);
        if (within < CAP)
            packed[(long long)bk * CAP + within] = staged[i];
    }
}

// ---------------------------------------------------------------------------
// Per-node feature transform (layer 1 only): h = x @ W; alpha dots.
// Writes h in fp32 (self-term) AND fp16 (h16, 3.2MB gather table).
template <int NF>
__global__ void feat_kernel(const float* __restrict__ x, const float* __restrict__ W,
                            const float* __restrict__ avs, const float* __restrict__ avd,
                            float* __restrict__ h, __half* __restrict__ h16,
                            float* __restrict__ as, float* __restrict__ ad, int n) {
    __shared__ float sW[NF * 16];
    __shared__ float sa[32];
    int t = threadIdx.x;
    if (t < NF * 16) sW[t] = W[t];
    if (t < 16) sa[t] = avs[t];
    else if (t < 32) sa[t] = avd[t - 16];
    __syncthreads();
    int nid = blockIdx.x * blockDim.x + t;
    if (nid >= n) return;
    float xi[NF];
#pragma unroll
    for (int f = 0; f < NF; ++f) xi[f] = x[(long long)nid * NF + f];
    float hv[16];
    float s1 = 0.f, s2 = 0.f;
#pragma unroll
    for (int k = 0; k < 16; ++k) {
        float acc = 0.f;
#pragma unroll
        for (int f = 0; f < NF; ++f) acc = fmaf(xi[f], sW[f * 16 + k], acc);
        hv[k] = acc;
        s1 = fmaf(acc, sa[k], s1);
        s2 = fmaf(acc, sa[16 + k], s2);
    }
    float4* hp = (float4*)(h + (long long)nid * 16);
    hp[0] = make_float4(hv[0], hv[1], hv[2], hv[3]);
    hp[1] = make_float4(hv[4], hv[5], hv[6], hv[7]);
    hp[2] = make_float4(hv[8], hv[9], hv[10], hv[11]);
    hp[3] = make_float4(hv[12], hv[13], hv[14], hv[15]);
    unsigned u[8];
#pragma unroll
    for (int q = 0; q < 8; ++q) {
        __half2 p2 = __halves2half2(__float2half(hv[2 * q]), __float2half(hv[2 * q + 1]));
        u[q] = *(unsigned*)&p2;
    }
    uint4* hp16 = (uint4*)(h16 + (long long)nid * 16);
    hp16[0] = make_uint4(u[0], u[1], u[2], u[3]);
    hp16[1] = make_uint4(u[4], u[5], u[6], u[7]);
    as[nid] = s1;
    ad[nid] = s2;
}

// ---------------------------------------------------------------------------
// EDGE-PARALLEL two-pass softmax aggregation (R21-validated form), one
// 1024-thread block per bucket. Pass 1: per-node TRUE max via one LDS u32
// atomicMax per edge (exact, commutative); weights w = exp(e - m + 21 ln2)
// <= 2^21 so per-node channel sums < 2^30 and TWO channels fit one u64
// atomic: enc = (t1<<32) + (t0 + 2^31), added mod 2^64; the addend count
// (den high word) recovers exact carries at output. 9 u64 + 1 u32 atomics
// per edge, iterations fully independent (no serial walk — R22's sorted
// register-flush regressed 2x from the divergent dependent-load chain).
// BITWISE ORDER-INDEPENDENT: integer max/add commute exactly. den >= 2^21
// => quantization ~1.5e-5.
// FUSE=1: instead of writing layer-1 output, the epilogue computes the
// layer-2 feature transform per node (o = relu(acc/den + b1); h2 = o @ W2;
// alpha dots) straight from LDS and writes hO/h16O/asO/adO — deletes the
// feat<16> dispatch and the h1 round-trip. Output buffers are distinct from
// the input h/h16/as/ad arrays (other blocks still read those).
template <int FUSE>
__global__ void __launch_bounds__(1024) aggr_kernel(
        const float* __restrict__ h, const __half* __restrict__ h16,
        const float* __restrict__ as, const float* __restrict__ ad,
        const unsigned* __restrict__ packed, const int* __restrict__ bfill,
        const float* __restrict__ bias,
        const float* __restrict__ W2, const float* __restrict__ avs2,
        const float* __restrict__ avd2,
        float* __restrict__ hO, __half* __restrict__ h16O,
        float* __restrict__ asO, float* __restrict__ adO,
        float* __restrict__ out, int n) {
    __shared__ unsigned long long accS[NPB * 9];  // 18KB: +0..7 ch-pairs, +8 cnt|den
    __shared__ unsigned maxS[NPB];                // fkey(per-node max e)
    __shared__ float ccS[NPB];
    __shared__ float adnS[NPB];
    __shared__ float sW2[256];
    __shared__ float sa2[32];
    int b = blockIdx.x, t = threadIdx.x;
    if constexpr (FUSE) {
        if (t < 256) sW2[t] = W2[t];
        else if (t < 272) sa2[t - 256] = avs2[t - 256];
        else if (t < 288) sa2[t - 272 + 16] = avd2[t - 272];
    }
    int cnt = min(bfill[b], CAP);
    long long pb = (long long)b * CAP;
    // (a) init per-node state: adn + max seeded with self score
    if (t < NPB) {
        int node = b * NPB + t;
        float adn = (node < n) ? ad[node] : 0.f;
        adnS[t] = adn;
        float es = (node < n) ? (as[node] + adn) : 0.f;
        es = fmaxf(es, SLOPE * es);
        maxS[t] = fkey(es);
    }
    __syncthreads();
    // (b) pass 1: per-node true max over edges; keep (packed,e) in regs
    unsigned pk[10];
    float ev[10];
#pragma unroll
    for (int r = 0; r < 10; ++r) {
        int j = t + (r << 10);
        pk[r] = 0xFFFFFFFFu;
        if (j < cnt) {
            unsigned p = packed[pb + j];
            int dl = p >> 17;
            int s = (int)(p & 0x1FFFF);
            float e2 = as[s] + adnS[dl];
            e2 = fmaxf(e2, SLOPE * e2);
            pk[r] = p;
            ev[r] = e2;
            atomicMax(&maxS[dl], fkey(e2));
        }
    }
    __syncthreads();
    // (c) per-node cc + self term (count starts at 1)
    if (t < NPB) {
        int node = b * NPB + t;
        if (node < n) {
            float m = fdekey(maxS[t]);
            float cc = 21.f * 0.69314718f - m;   // w = exp(e+cc) <= 2^21
            ccS[t] = cc;
            float es = as[node] + adnS[t];
            es = fmaxf(es, SLOPE * es);
            float ws = __expf(es + cc);
            unsigned wsi = (unsigned)(int)ws;
            int base = t * 9;
            const float4* hp = (const float4*)(h + (long long)node * 16);
            float4 h0 = hp[0], h1v = hp[1], h2v = hp[2], h3v = hp[3];
            float hv[16] = {h0.x, h0.y, h0.z, h0.w, h1v.x, h1v.y, h1v.z, h1v.w,
                            h2v.x, h2v.y, h2v.z, h2v.w, h3v.x, h3v.y, h3v.z, h3v.w};
#pragma unroll
            for (int q = 0; q < 8; ++q) {
                int t0 = (int)(ws * hv[2 * q]);
                int t1 = (int)(ws * hv[2 * q + 1]);
                accS[base + q] = ((unsigned long long)(unsigned)t1 << 32) +
                                 (unsigned long long)((unsigned)t0 + 0x80000000u);
            }
            accS[base + 8] = (1ull << 32) | wsi;  // count=1, den=ws
        }
    }
    __syncthreads();
    // (d) pass 2: exp + packed-pair atomics (9 u64 + independent iterations)
#pragma unroll
    for (int r = 0; r < 10; ++r) {
        if (pk[r] != 0xFFFFFFFFu) {
            unsigned p = pk[r];
            int dl = p >> 17;
            int s = (int)(p & 0x1FFFF);
            float w = __expf(ev[r] + ccS[dl]);
            unsigned wi = (unsigned)(int)w;
            int base = dl * 9;
            atomicAdd(&accS[base + 8], (1ull << 32) | wi);
            const uint4* hr = (const uint4*)(h16 + (long long)s * 16);
            uint4 r0 = hr[0], r1 = hr[1];
            unsigned rr[8] = {r0.x, r0.y, r0.z, r0.w, r1.x, r1.y, r1.z, r1.w};
#pragma unroll
            for (int q = 0; q < 8; ++q) {
                float2 f = __half22float2(*(__half2*)&rr[q]);
                int t0 = (int)(w * f.x);
                int t1 = (int)(w * f.y);
                unsigned long long enc =
                    ((unsigned long long)(unsigned)t1 << 32) +
                    (unsigned long long)((unsigned)t0 + 0x80000000u);
                atomicAdd(&accS[base + q], enc);
            }
        }
    }
    __syncthreads();
    // (e) output
    if constexpr (FUSE) {
        // layer-1 finish + fused layer-2 feature transform, per node
        if (t < NPB) {
            int node = b * NPB + t;
            if (node < n) {
                unsigned long long dpack = accS[t * 9 + 8];
                unsigned kcnt = (unsigned)(dpack >> 32);
                float den = (float)(unsigned)dpack;
                float o[16];
#pragma unroll
                for (int q = 0; q < 8; ++q) {
                    unsigned long long a = accS[t * 9 + q];
                    unsigned lo = (unsigned)a, hi = (unsigned)(a >> 32);
                    int s0 = (int)(lo - (kcnt << 31));
                    long long carries =
                        ((((long long)kcnt) << 31) + (long long)s0) >> 32;
                    int s1v = (int)(hi - (unsigned)carries);
                    o[2 * q]     = fmaxf((float)s0  / den + bias[2 * q], 0.f);
                    o[2 * q + 1] = fmaxf((float)s1v / den + bias[2 * q + 1], 0.f);
                }
                float hv[16];
                float d1 = 0.f, d2 = 0.f;
#pragma unroll
                for (int k = 0; k < 16; ++k) {
                    float acc = 0.f;
#pragma unroll
                    for (int f = 0; f < 16; ++f)
                        acc = fmaf(o[f], sW2[f * 16 + k], acc);
                    hv[k] = acc;
                    d1 = fmaf(acc, sa2[k], d1);
                    d2 = fmaf(acc, sa2[16 + k], d2);
                }
                float4* hp = (float4*)(hO + (long long)node * 16);
                hp[0] = make_float4(hv[0], hv[1], hv[2], hv[3]);
                hp[1] = make_float4(hv[4], hv[5], hv[6], hv[7]);
                hp[2] = make_float4(hv[8], hv[9], hv[10], hv[11]);
                hp[3] = make_float4(hv[12], hv[13], hv[14], hv[15]);
                unsigned u[8];
#pragma unroll
                for (int q = 0; q < 8; ++q) {
                    __half2 p2 = __halves2half2(__float2half(hv[2 * q]),
                                                __float2half(hv[2 * q + 1]));
                    u[q] = *(unsigned*)&p2;
                }
                uint4* hp16 = (uint4*)(h16O + (long long)node * 16);
                hp16[0] = make_uint4(u[0], u[1], u[2], u[3]);
                hp16[1] = make_uint4(u[4], u[5], u[6], u[7]);
                asO[node] = d1;
                adO[node] = d2;
            }
        }
    } else {
        // final layer: unpack, divide, bias (no relu), coalesced store
        for (int idx = t; idx < NPB * 16; idx += 1024) {
            int i = idx >> 4, k = idx & 15;
            int node = b * NPB + i;
            if (node < n) {
                unsigned long long dpack = accS[i * 9 + 8];
                unsigned kcnt = (unsigned)(dpack >> 32);
                float den = (float)(unsigned)dpack;
                unsigned long long a = accS[i * 9 + (k >> 1)];
                unsigned lo = (unsigned)a, hi = (unsigned)(a >> 32);
                int s0 = (int)(lo - (kcnt << 31));
                float val;
                if ((k & 1) == 0) {
                    val = (float)s0;
                } else {
                    long long carries =
                        ((((long long)kcnt) << 31) + (long long)s0) >> 32;
                    int s1v = (int)(hi - (unsigned)carries);
                    val = (float)s1v;
                }
                out[(long long)node * 16 + k] = val / den + bias[k];
            }
        }
    }
}

// ---------------------------------------------------------------------------
extern "C" void kernel_launch(void* const* d_in, const int* in_sizes, int n_in,
                              void* d_out, int out_size, void* d_ws, size_t ws_size,
                              hipStream_t stream) {
    const float* x  = (const float*)d_in[0];
    const void*  ei = d_in[1];
    const float* W1  = (const float*)d_in[2];
    const float* as1 = (const float*)d_in[3];
    const float* ad1 = (const float*)d_in[4];
    const float* b1  = (const float*)d_in[5];
    const float* W2  = (const float*)d_in[6];
    const float* as2 = (const float*)d_in[7];
    const float* ad2 = (const float*)d_in[8];
    const float* b2  = (const float*)d_in[9];
    float* out = (float*)d_out;

    const int n = in_sizes[0] / 14;      // 100000
    const int e = in_sizes[1] / 2;       // 3200000
    const int nb = (n + NPB - 1) / NPB;  // 391 buckets

    char* p = (char*)d_ws;
    auto alloc = [&](size_t bytes) {
        char* r = p;
        p += (bytes + 255) & ~(size_t)255;
        return r;
    };
    int*      bfill  = (int*)alloc(NBMAX * 4);
    unsigned* packed = (unsigned*)alloc((size_t)nb * CAP * 4);
    float*    hA     = (float*)alloc((size_t)n * 16 * 4);
    __half*   h16A   = (__half*)alloc((size_t)n * 16 * 2);
    float*    asA    = (float*)alloc((size_t)n * 4);
    float*    adA    = (float*)alloc((size_t)n * 4);
    float*    hB     = (float*)alloc((size_t)n * 16 * 4);
    __half*   h16B   = (__half*)alloc((size_t)n * 16 * 2);
    float*    asB    = (float*)alloc((size_t)n * 4);
    float*    adB    = (float*)alloc((size_t)n * 4);

    zero_kernel<<<1, 256, 0, stream>>>(bfill);
    bin_kernel<<<(e + EPB - 1) / EPB, 1024, 0, stream>>>(ei, bfill, packed, e, nb);

    // Layer 1 feature transform
    feat_kernel<14><<<(n + 255) / 256, 256, 0, stream>>>(x, W1, as1, ad1, hA, h16A, asA, adA, n);
    // Layer-1 aggregation fused with layer-2 feature transform
    aggr_kernel<1><<<nb, 1024, 0, stream>>>(hA, h16A, asA, adA, packed, bfill, b1,
                                            W2, as2, ad2, hB, h16B, asB, adB,
                                            nullptr, n);
    // Layer-2 aggregation -> final output
    aggr_kernel<0><<<nb, 1024, 0, stream>>>(hB, h16B, asB, adB, packed, bfill, b2,
                                            nullptr, nullptr, nullptr,
                                            nullptr, nullptr, nullptr, nullptr,
                                            out, n);
}